// Round 4
// baseline (825.205 us; speedup 1.0000x reference)
//
#include <hip/hip_runtime.h>
#include <cmath>

#define CIN   512
#define COUT  64
#define DBINS 41
#define NFEAT 105   // DBINS + COUT
#define HF    16
#define WF    44
#define NPIX  704   // HF*WF
#define NCAM  24    // B*N
#define NXG   128
#define NVOX  16384 // 128*128 (NX2 == 1)
#define ROWF  210   // per-pixel feat row: [kh=0: 105][kh=1: 105]
#define NPAIR (NCAM * NPIX * DBINS)  // 692736

// Workspace layout (bytes):
//   cams  @ 0        (4608 used, 8192 reserved)
//   feat  @ 8192     16896*210*4 = 14,192,640   [pix][210]
//   cnt   @ 14,200,832   16384*4 = 65,536
//   offs  @ 14,266,368   16384*4 = 65,536
//   rec   @ 14,331,904   692736*4 = 2,770,944   (total 17,102,848 <= known-safe 18.4 MB)
#define WS_FEAT 8192
#define WS_CNT  14200832
#define WS_OFFS 14266368
#define WS_REC  14331904

// ---------------------------------------------------------------- utilities
__device__ __forceinline__ void inv3(const double a[9], double o[9]) {
    double c00 =  a[4]*a[8] - a[5]*a[7];
    double c01 = -(a[3]*a[8] - a[5]*a[6]);
    double c02 =  a[3]*a[7] - a[4]*a[6];
    double det = a[0]*c00 + a[1]*c01 + a[2]*c02;
    double id  = 1.0 / det;
    o[0] = c00 * id;
    o[1] = -(a[1]*a[8] - a[2]*a[7]) * id;
    o[2] =  (a[1]*a[5] - a[2]*a[4]) * id;
    o[3] = c01 * id;
    o[4] =  (a[0]*a[8] - a[2]*a[6]) * id;
    o[5] = -(a[0]*a[5] - a[2]*a[3]) * id;
    o[6] = c02 * id;
    o[7] = -(a[0]*a[7] - a[1]*a[6]) * id;
    o[8] =  (a[0]*a[4] - a[1]*a[3]) * id;
}

// --------------------------------------------------------- per-camera setup
__global__ void setup_cams_k(const float* __restrict__ rots,
                             const float* __restrict__ trans,
                             const float* __restrict__ intrins,
                             const float* __restrict__ post_rots,
                             const float* __restrict__ post_trans,
                             double* __restrict__ cams) {
    int i = blockIdx.x * blockDim.x + threadIdx.x;
    if (i >= NCAM) return;
    double R[9], K[9], PR[9], Kinv[9], PRinv[9];
    for (int k = 0; k < 9; ++k) {
        R[k]  = (double)rots[i*9 + k];
        K[k]  = (double)intrins[i*9 + k];
        PR[k] = (double)post_rots[i*9 + k];
    }
    inv3(K, Kinv);
    inv3(PR, PRinv);
    double* o = cams + (size_t)i * 24;
    for (int k = 0; k < 9; ++k) o[k] = PRinv[k];
    o[9]  = (double)post_trans[i*3 + 0];
    o[10] = (double)post_trans[i*3 + 1];
    o[11] = (double)post_trans[i*3 + 2];
    for (int r = 0; r < 3; ++r)
        for (int c = 0; c < 3; ++c)
            o[12 + r*3 + c] = R[r*3+0]*Kinv[0*3+c] + R[r*3+1]*Kinv[1*3+c] + R[r*3+2]*Kinv[2*3+c];
    o[21] = (double)trans[i*3 + 0];
    o[22] = (double)trans[i*3 + 1];
    o[23] = (double)trans[i*3 + 2];
}

// --------------------------------------------------------------- 1x1 conv GEMM
// x: [NCAM][CIN][NPIX], w: [NFEAT][CIN], feat row: [pix][kh*105 + o]
__global__ __launch_bounds__(512) void gemm_feat_k(const float* __restrict__ x,
                                                   const float* __restrict__ w,
                                                   const float* __restrict__ bias,
                                                   float* __restrict__ feat) {
    __shared__ float xs[16][64][4];   // 16 KB
    __shared__ float wsm[64 * 113];   // w-tile [112][64], then out-tile [64][113]

    int bx   = blockIdx.x;            // 0..527
    int kh   = bx & 1;
    int tile = bx >> 1;               // 0..263
    int bn   = tile / 11;
    int p0   = (tile - bn * 11) * 64;
    int lane = threadIdx.x & 63;      // px within tile
    int wid  = threadIdx.x >> 6;      // 0..7 -> out group of 14

    float acc[14];
    #pragma unroll
    for (int i = 0; i < 14; ++i) acc[i] = 0.0f;

    for (int kt = 0; kt < 4; ++kt) {
        int kbase = kh * 256 + kt * 64;
        #pragma unroll
        for (int pass = 0; pass < 2; ++pass) {
            int idx = threadIdx.x + pass * 512;   // 0..1023
            int px  = idx & 63;
            int kq  = idx >> 6;                   // 0..15
            const float* g = x + ((size_t)bn * CIN + kbase + (kq << 2)) * NPIX + p0 + px;
            xs[kq][px][0] = g[0 * NPIX];
            xs[kq][px][1] = g[1 * NPIX];
            xs[kq][px][2] = g[2 * NPIX];
            xs[kq][px][3] = g[3 * NPIX];
        }
        #pragma unroll
        for (int pass = 0; pass < 4; ++pass) {
            int idx = threadIdx.x + pass * 512;   // 0..2047
            int o   = idx >> 4;                   // 0..127
            int ci  = (idx & 15) << 2;
            if (o < 112) {
                float4 wv = make_float4(0.f, 0.f, 0.f, 0.f);
                if (o < 105)
                    wv = *reinterpret_cast<const float4*>(w + (size_t)o * CIN + kbase + ci);
                *reinterpret_cast<float4*>(&wsm[o * 64 + ci]) = wv;
            }
        }
        __syncthreads();
        #pragma unroll 4
        for (int kq = 0; kq < 16; ++kq) {
            float4 xv = *reinterpret_cast<const float4*>(&xs[kq][lane][0]);
            #pragma unroll
            for (int i = 0; i < 14; ++i) {
                float4 wv = *reinterpret_cast<const float4*>(&wsm[(wid * 14 + i) * 64 + (kq << 2)]);
                acc[i] = fmaf(xv.x, wv.x, acc[i]);
                acc[i] = fmaf(xv.y, wv.y, acc[i]);
                acc[i] = fmaf(xv.z, wv.z, acc[i]);
                acc[i] = fmaf(xv.w, wv.w, acc[i]);
            }
        }
        __syncthreads();
    }

    // epilogue via padded LDS tile, store to interleaved rows (stride 210)
    #pragma unroll
    for (int i = 0; i < 14; ++i) {
        int o = wid * 14 + i;
        if (o < NFEAT) {
            float b = (kh == 0) ? bias[o] : 0.0f;
            wsm[lane * 113 + o] = acc[i] + b;
        }
    }
    __syncthreads();
    float* dst = feat + ((size_t)bn * NPIX + p0) * ROWF + kh * NFEAT;
    for (int idx = threadIdx.x; idx < 64 * NFEAT; idx += 512) {
        int px = idx / NFEAT;
        int o  = idx - px * NFEAT;
        dst[(size_t)px * ROWF + o] = wsm[px * 113 + o];
    }
}

// -------------------------------------------- softmax + geometry, in-place
// Row rewritten as: [0..63]=folded channels, [64..104]=depth weights,
// [105..145]=rank (int, -1 invalid). cnt[r] counts contributions.
__global__ __launch_bounds__(64) void phaseA_k(float* __restrict__ feat,
                                               const double* __restrict__ cams,
                                               int* __restrict__ cnt) {
    int pix = blockIdx.x;            // 0..16895
    int bn  = pix / NPIX;
    int p   = pix - bn * NPIX;
    int h   = p / WF;
    int wpx = p - h * WF;
    int lane = threadIdx.x;

    __shared__ float f[NFEAT];
    float* row = feat + (size_t)pix * ROWF;
    for (int o = lane; o < NFEAT; o += 64) f[o] = row[o] + row[NFEAT + o];
    __syncthreads();   // also drains the global reads before we overwrite row

    // softmax over f[0..40]
    float v = (lane < DBINS) ? f[lane] : -1e30f;
    float m = v;
    #pragma unroll
    for (int o = 32; o > 0; o >>= 1) m = fmaxf(m, __shfl_xor(m, o, 64));
    float e = (lane < DBINS) ? expf(v - m) : 0.0f;
    float s = e;
    #pragma unroll
    for (int o = 32; o > 0; o >>= 1) s += __shfl_xor(s, o, 64);

    if (lane < DBINS) {
        float pd = e / s;
        const double* cm = cams + (size_t)bn * 24;
        double dd = 4.0 + (double)lane;
        double ax = (double)wpx - cm[9];
        double ay = (double)h   - cm[10];
        double az = dd          - cm[11];
        double q0 = cm[0]*ax + cm[1]*ay + cm[2]*az;
        double q1 = cm[3]*ax + cm[4]*ay + cm[5]*az;
        double q2 = cm[6]*ax + cm[7]*ay + cm[8]*az;
        double r0 = q0 * q2, r1 = q1 * q2, r2 = q2;
        double sx = cm[12]*r0 + cm[13]*r1 + cm[14]*r2 + cm[21];
        double sy = cm[15]*r0 + cm[16]*r1 + cm[17]*r2 + cm[22];
        double sz = cm[18]*r0 + cm[19]*r1 + cm[20]*r2 + cm[23];
        int cx = (int)((sx + 50.8) / 0.8);   // trunc == .astype(int32)
        int cy = (int)((sy + 50.8) / 0.8);
        int cz = (int)(sz / 20.0);
        bool ok = (cx >= 0) && (cx < NXG) && (cy >= 0) && (cy < NXG) && (cz == 0);
        int rk = ok ? (cy * NXG + cx) : -1;
        row[64 + lane] = pd;
        ((int*)row)[105 + lane] = rk;
        if (rk >= 0) atomicAdd(&cnt[rk], 1);
    }
    row[lane] = f[DBINS + lane];   // folded channel vector
}

// ------------------------------------------------- exclusive scan of cnt
__global__ __launch_bounds__(1024) void scan_k(const int* __restrict__ cnt,
                                               int* __restrict__ offs) {
    __shared__ int sc[1024];
    int t = threadIdx.x;
    int loc[16];
    int s = 0;
    #pragma unroll
    for (int j = 0; j < 16; ++j) { loc[j] = cnt[t*16 + j]; s += loc[j]; }
    sc[t] = s;
    __syncthreads();
    for (int off = 1; off < 1024; off <<= 1) {
        int add = (t >= off) ? sc[t - off] : 0;
        __syncthreads();
        sc[t] += add;
        __syncthreads();
    }
    int base = sc[t] - s;                  // exclusive block prefix
    #pragma unroll
    for (int j = 0; j < 16; ++j) { offs[t*16 + j] = base; base += loc[j]; }
}

// ------------------------------------------------- place pairs into segments
// offs[r] advances to its segment END; start of r = offs[r-1] afterwards.
__global__ __launch_bounds__(256) void place_k(const float* __restrict__ feat,
                                               int* __restrict__ offs,
                                               unsigned* __restrict__ rec) {
    int i = blockIdx.x * 256 + threadIdx.x;
    if (i >= NPAIR) return;
    int pix = i / DBINS;
    int d   = i - pix * DBINS;
    const int* rowI = (const int*)(feat + (size_t)pix * ROWF);
    int r = rowI[105 + d];
    if (r >= 0) {
        int pos = atomicAdd(&offs[r], 1);
        rec[pos] = ((unsigned)pix << 6) | (unsigned)d;
    }
}

// ------------------------------------------------- gather + fused transpose
// One wave per voxel (round-robin over 4 waves), lane = channel; direct out write.
__global__ __launch_bounds__(256) void gather_k(const float* __restrict__ feat,
                                                const int* __restrict__ offs,
                                                const unsigned* __restrict__ rec,
                                                float* __restrict__ out) {
    __shared__ float tile[64][65];
    int r0   = blockIdx.x * 64;
    int wv   = threadIdx.x >> 6;
    int lane = threadIdx.x & 63;
    for (int k = 0; k < 16; ++k) {
        int v = wv + 4 * k;
        int r = r0 + v;
        int start = (r == 0) ? 0 : offs[r - 1];
        int end   = offs[r];
        float acc = 0.0f;
        for (int i = start; i < end; ++i) {
            unsigned e = rec[i];
            const float* base = feat + (size_t)(e >> 6) * ROWF;
            acc = fmaf(base[64 + (e & 63u)], base[lane], acc);
        }
        tile[v][lane] = acc;
    }
    __syncthreads();
    #pragma unroll
    for (int k = 0; k < 16; ++k) {
        int ch = wv + 4 * k;
        out[(size_t)ch * NVOX + r0 + lane] = tile[lane][ch];
    }
}

// --------------------------------------------------------------------- launch
extern "C" void kernel_launch(void* const* d_in, const int* in_sizes, int n_in,
                              void* d_out, int out_size, void* d_ws, size_t ws_size,
                              hipStream_t stream) {
    const float* img   = (const float*)d_in[0];
    const float* dw    = (const float*)d_in[1];
    const float* db    = (const float*)d_in[2];
    const float* rots  = (const float*)d_in[3];
    const float* trans = (const float*)d_in[4];
    const float* intr  = (const float*)d_in[5];
    const float* prot  = (const float*)d_in[6];
    const float* ptrn  = (const float*)d_in[7];
    float* out = (float*)d_out;

    char* ws = (char*)d_ws;
    double*   cams = (double*)ws;
    float*    feat = (float*)(ws + WS_FEAT);
    int*      cnt  = (int*)(ws + WS_CNT);
    int*      offs = (int*)(ws + WS_OFFS);
    unsigned* rec  = (unsigned*)(ws + WS_REC);

    hipMemsetAsync(cnt, 0, NVOX * sizeof(int), stream);
    setup_cams_k<<<1, 64, 0, stream>>>(rots, trans, intr, prot, ptrn, cams);
    gemm_feat_k<<<528, 512, 0, stream>>>(img, dw, db, feat);
    phaseA_k<<<NCAM * NPIX, 64, 0, stream>>>(feat, cams, cnt);
    scan_k<<<1, 1024, 0, stream>>>(cnt, offs);
    place_k<<<(NPAIR + 255) / 256, 256, 0, stream>>>(feat, offs, rec);
    gather_k<<<NVOX / 64, 256, 0, stream>>>(feat, offs, rec, out);
}

// Round 5
// 272.323 us; speedup vs baseline: 3.0302x; 3.0302x over previous
//
#include <hip/hip_runtime.h>
#include <cmath>

#define CIN   512
#define COUT  64
#define DBINS 41
#define NFEAT 105   // DBINS + COUT
#define HF    16
#define WF    44
#define NPIX  704   // HF*WF
#define NCAM  24    // B*N
#define NXG   128
#define NVOX  16384 // 128*128 (NX2 == 1)
#define ROWF  210   // per-pixel feat row
#define BEVOF 146   // row tail offset: 64-float BEV accumulator per voxel
#define NPAIR (NCAM * NPIX * DBINS)  // 692736

// Workspace layout (bytes) — identical to round 4 (validated size):
#define WS_FEAT 8192
#define WS_CNT  14200832
#define WS_OFFS 14266368
#define WS_REC  14331904

// ---------------------------------------------------------------- utilities
__device__ __forceinline__ void inv3(const double a[9], double o[9]) {
    double c00 =  a[4]*a[8] - a[5]*a[7];
    double c01 = -(a[3]*a[8] - a[5]*a[6]);
    double c02 =  a[3]*a[7] - a[4]*a[6];
    double det = a[0]*c00 + a[1]*c01 + a[2]*c02;
    double id  = 1.0 / det;
    o[0] = c00 * id;
    o[1] = -(a[1]*a[8] - a[2]*a[7]) * id;
    o[2] =  (a[1]*a[5] - a[2]*a[4]) * id;
    o[3] = c01 * id;
    o[4] =  (a[0]*a[8] - a[2]*a[6]) * id;
    o[5] = -(a[0]*a[5] - a[2]*a[3]) * id;
    o[6] = c02 * id;
    o[7] = -(a[0]*a[7] - a[1]*a[6]) * id;
    o[8] =  (a[0]*a[4] - a[1]*a[3]) * id;
}

// --------------------------------------------------------- per-camera setup
__global__ void setup_cams_k(const float* __restrict__ rots,
                             const float* __restrict__ trans,
                             const float* __restrict__ intrins,
                             const float* __restrict__ post_rots,
                             const float* __restrict__ post_trans,
                             double* __restrict__ cams) {
    int i = blockIdx.x * blockDim.x + threadIdx.x;
    if (i >= NCAM) return;
    double R[9], K[9], PR[9], Kinv[9], PRinv[9];
    for (int k = 0; k < 9; ++k) {
        R[k]  = (double)rots[i*9 + k];
        K[k]  = (double)intrins[i*9 + k];
        PR[k] = (double)post_rots[i*9 + k];
    }
    inv3(K, Kinv);
    inv3(PR, PRinv);
    double* o = cams + (size_t)i * 24;
    for (int k = 0; k < 9; ++k) o[k] = PRinv[k];
    o[9]  = (double)post_trans[i*3 + 0];
    o[10] = (double)post_trans[i*3 + 1];
    o[11] = (double)post_trans[i*3 + 2];
    for (int r = 0; r < 3; ++r)
        for (int c = 0; c < 3; ++c)
            o[12 + r*3 + c] = R[r*3+0]*Kinv[0*3+c] + R[r*3+1]*Kinv[1*3+c] + R[r*3+2]*Kinv[2*3+c];
    o[21] = (double)trans[i*3 + 0];
    o[22] = (double)trans[i*3 + 1];
    o[23] = (double)trans[i*3 + 2];
}

// --------------------------------------------------------------- 1x1 conv GEMM
__global__ __launch_bounds__(512) void gemm_feat_k(const float* __restrict__ x,
                                                   const float* __restrict__ w,
                                                   const float* __restrict__ bias,
                                                   float* __restrict__ feat) {
    __shared__ float xs[16][64][4];
    __shared__ float wsm[64 * 113];

    int bx   = blockIdx.x;
    int kh   = bx & 1;
    int tile = bx >> 1;
    int bn   = tile / 11;
    int p0   = (tile - bn * 11) * 64;
    int lane = threadIdx.x & 63;
    int wid  = threadIdx.x >> 6;

    float acc[14];
    #pragma unroll
    for (int i = 0; i < 14; ++i) acc[i] = 0.0f;

    for (int kt = 0; kt < 4; ++kt) {
        int kbase = kh * 256 + kt * 64;
        #pragma unroll
        for (int pass = 0; pass < 2; ++pass) {
            int idx = threadIdx.x + pass * 512;
            int px  = idx & 63;
            int kq  = idx >> 6;
            const float* g = x + ((size_t)bn * CIN + kbase + (kq << 2)) * NPIX + p0 + px;
            xs[kq][px][0] = g[0 * NPIX];
            xs[kq][px][1] = g[1 * NPIX];
            xs[kq][px][2] = g[2 * NPIX];
            xs[kq][px][3] = g[3 * NPIX];
        }
        #pragma unroll
        for (int pass = 0; pass < 4; ++pass) {
            int idx = threadIdx.x + pass * 512;
            int o   = idx >> 4;
            int ci  = (idx & 15) << 2;
            if (o < 112) {
                float4 wv = make_float4(0.f, 0.f, 0.f, 0.f);
                if (o < 105)
                    wv = *reinterpret_cast<const float4*>(w + (size_t)o * CIN + kbase + ci);
                *reinterpret_cast<float4*>(&wsm[o * 64 + ci]) = wv;
            }
        }
        __syncthreads();
        #pragma unroll 4
        for (int kq = 0; kq < 16; ++kq) {
            float4 xv = *reinterpret_cast<const float4*>(&xs[kq][lane][0]);
            #pragma unroll
            for (int i = 0; i < 14; ++i) {
                float4 wv = *reinterpret_cast<const float4*>(&wsm[(wid * 14 + i) * 64 + (kq << 2)]);
                acc[i] = fmaf(xv.x, wv.x, acc[i]);
                acc[i] = fmaf(xv.y, wv.y, acc[i]);
                acc[i] = fmaf(xv.z, wv.z, acc[i]);
                acc[i] = fmaf(xv.w, wv.w, acc[i]);
            }
        }
        __syncthreads();
    }

    #pragma unroll
    for (int i = 0; i < 14; ++i) {
        int o = wid * 14 + i;
        if (o < NFEAT) {
            float b = (kh == 0) ? bias[o] : 0.0f;
            wsm[lane * 113 + o] = acc[i] + b;
        }
    }
    __syncthreads();
    float* dst = feat + ((size_t)bn * NPIX + p0) * ROWF + kh * NFEAT;
    for (int idx = threadIdx.x; idx < 64 * NFEAT; idx += 512) {
        int px = idx / NFEAT;
        int o  = idx - px * NFEAT;
        dst[(size_t)px * ROWF + o] = wsm[px * 113 + o];
    }
}

// -------------------------------------------- softmax + geometry, in-place
// Row rewritten as: [0..63]=folded channels, [64..104]=depth weights,
// [105..145]=rank (int, -1 invalid), [146..209]=BEV accumulator (zeroed).
__global__ __launch_bounds__(64) void phaseA_k(float* __restrict__ feat,
                                               const double* __restrict__ cams,
                                               int* __restrict__ cnt) {
    int pix = blockIdx.x;
    int bn  = pix / NPIX;
    int p   = pix - bn * NPIX;
    int h   = p / WF;
    int wpx = p - h * WF;
    int lane = threadIdx.x;

    __shared__ float f[NFEAT];
    float* row = feat + (size_t)pix * ROWF;
    for (int o = lane; o < NFEAT; o += 64) f[o] = row[o] + row[NFEAT + o];
    __syncthreads();   // all reads of row[] complete before any overwrite below

    float v = (lane < DBINS) ? f[lane] : -1e30f;
    float m = v;
    #pragma unroll
    for (int o = 32; o > 0; o >>= 1) m = fmaxf(m, __shfl_xor(m, o, 64));
    float e = (lane < DBINS) ? expf(v - m) : 0.0f;
    float s = e;
    #pragma unroll
    for (int o = 32; o > 0; o >>= 1) s += __shfl_xor(s, o, 64);

    if (lane < DBINS) {
        float pd = e / s;
        const double* cm = cams + (size_t)bn * 24;
        double dd = 4.0 + (double)lane;
        double ax = (double)wpx - cm[9];
        double ay = (double)h   - cm[10];
        double az = dd          - cm[11];
        double q0 = cm[0]*ax + cm[1]*ay + cm[2]*az;
        double q1 = cm[3]*ax + cm[4]*ay + cm[5]*az;
        double q2 = cm[6]*ax + cm[7]*ay + cm[8]*az;
        double r0 = q0 * q2, r1 = q1 * q2, r2 = q2;
        double sx = cm[12]*r0 + cm[13]*r1 + cm[14]*r2 + cm[21];
        double sy = cm[15]*r0 + cm[16]*r1 + cm[17]*r2 + cm[22];
        double sz = cm[18]*r0 + cm[19]*r1 + cm[20]*r2 + cm[23];
        int cx = (int)((sx + 50.8) / 0.8);   // trunc == .astype(int32)
        int cy = (int)((sy + 50.8) / 0.8);
        int cz = (int)(sz / 20.0);
        bool ok = (cx >= 0) && (cx < NXG) && (cy >= 0) && (cy < NXG) && (cz == 0);
        int rk = ok ? (cy * NXG + cx) : -1;
        row[64 + lane] = pd;
        ((int*)row)[105 + lane] = rk;
        if (rk >= 0) atomicAdd(&cnt[rk], 1);
    }
    row[lane] = f[DBINS + lane];   // folded channel vector
    row[BEVOF + lane] = 0.0f;      // zero this row's BEV accumulator slot
}

// ------------------------------------------------- exclusive scan of cnt
__global__ __launch_bounds__(1024) void scan_k(const int* __restrict__ cnt,
                                               int* __restrict__ offs) {
    __shared__ int sc[1024];
    int t = threadIdx.x;
    int loc[16];
    int s = 0;
    #pragma unroll
    for (int j = 0; j < 16; ++j) { loc[j] = cnt[t*16 + j]; s += loc[j]; }
    sc[t] = s;
    __syncthreads();
    for (int off = 1; off < 1024; off <<= 1) {
        int add = (t >= off) ? sc[t - off] : 0;
        __syncthreads();
        sc[t] += add;
        __syncthreads();
    }
    int base = sc[t] - s;
    #pragma unroll
    for (int j = 0; j < 16; ++j) { offs[t*16 + j] = base; base += loc[j]; }
}

// ------------------------------------------------- place pairs into segments
__global__ __launch_bounds__(256) void place_k(const float* __restrict__ feat,
                                               int* __restrict__ offs,
                                               unsigned* __restrict__ rec) {
    int i = blockIdx.x * 256 + threadIdx.x;
    if (i >= NPAIR) return;
    int pix = i / DBINS;
    int d   = i - pix * DBINS;
    const int* rowI = (const int*)(feat + (size_t)pix * ROWF);
    int r = rowI[105 + d];
    if (r >= 0) {
        int pos = atomicAdd(&offs[r], 1);
        rec[pos] = ((unsigned)pix << 6) | (unsigned)d;
    }
}

// ------------------------------------- entry-parallel segmented combine
// Grid-stride waves over 32-entry chunks of the rank-sorted rec stream.
// lane = channel; register-accumulate runs, atomic flush at rank boundaries
// into the feat-row-tail BEV accumulators.
__global__ __launch_bounds__(256) void combine_k(float* __restrict__ feat,
                                                 const int* __restrict__ offs,
                                                 const unsigned* __restrict__ rec) {
    int ncnt = offs[NVOX - 1];                 // total valid entries
    int lane = threadIdx.x & 63;
    int wave = (blockIdx.x << 2) + (threadIdx.x >> 6);
    int nwav = gridDim.x << 2;
    int nchunk = (ncnt + 31) >> 5;

    for (int ch = wave; ch < nchunk; ch += nwav) {
        int i0 = ch << 5;
        int n  = min(32, ncnt - i0);
        // lanes 0..n-1 load meta for entry i0+lane
        int   rv = -1, pv = 0;
        float wv = 0.0f;
        if (lane < n) {
            unsigned e = rec[i0 + lane];
            pv = (int)(e >> 6);
            int d = (int)(e & 63u);
            const float* row = feat + (size_t)pv * ROWF;
            rv = ((const int*)row)[105 + d];
            wv = row[64 + d];
        }
        float acc = 0.0f;
        for (int j = 0; j < n; ++j) {
            int   rj = __shfl(rv, j, 64);
            float wj = __shfl(wv, j, 64);
            int   pj = __shfl(pv, j, 64);
            acc = fmaf(wj, feat[(size_t)pj * ROWF + lane], acc);
            int rn = __shfl(rv, (j + 1) & 31, 64);
            if (j == n - 1 || rn != rj) {
                atomicAdd(&feat[(size_t)rj * ROWF + BEVOF + lane], acc);
                acc = 0.0f;
            }
        }
    }
}

// -------------------------------------------------------- bev tails -> out
__global__ __launch_bounds__(256) void transpose_k(const float* __restrict__ feat,
                                                   float* __restrict__ out) {
    __shared__ float t[64][65];
    int r0 = blockIdx.x * 64;
    int c  = threadIdx.x & 63;
    int r4 = threadIdx.x >> 6;
    #pragma unroll
    for (int i = 0; i < 16; ++i) {
        int r = r4 + i * 4;
        t[r][c] = feat[(size_t)(r0 + r) * ROWF + BEVOF + c];
    }
    __syncthreads();
    int rl  = threadIdx.x & 63;
    int cc0 = threadIdx.x >> 6;
    #pragma unroll
    for (int i = 0; i < 16; ++i) {
        int ch = cc0 + i * 4;
        out[(size_t)ch * NVOX + r0 + rl] = t[rl][ch];
    }
}

// --------------------------------------------------------------------- launch
extern "C" void kernel_launch(void* const* d_in, const int* in_sizes, int n_in,
                              void* d_out, int out_size, void* d_ws, size_t ws_size,
                              hipStream_t stream) {
    const float* img   = (const float*)d_in[0];
    const float* dw    = (const float*)d_in[1];
    const float* db    = (const float*)d_in[2];
    const float* rots  = (const float*)d_in[3];
    const float* trans = (const float*)d_in[4];
    const float* intr  = (const float*)d_in[5];
    const float* prot  = (const float*)d_in[6];
    const float* ptrn  = (const float*)d_in[7];
    float* out = (float*)d_out;

    char* ws = (char*)d_ws;
    double*   cams = (double*)ws;
    float*    feat = (float*)(ws + WS_FEAT);
    int*      cnt  = (int*)(ws + WS_CNT);
    int*      offs = (int*)(ws + WS_OFFS);
    unsigned* rec  = (unsigned*)(ws + WS_REC);

    hipMemsetAsync(cnt, 0, NVOX * sizeof(int), stream);
    setup_cams_k<<<1, 64, 0, stream>>>(rots, trans, intr, prot, ptrn, cams);
    gemm_feat_k<<<528, 512, 0, stream>>>(img, dw, db, feat);
    phaseA_k<<<NCAM * NPIX, 64, 0, stream>>>(feat, cams, cnt);
    scan_k<<<1, 1024, 0, stream>>>(cnt, offs);
    place_k<<<(NPAIR + 255) / 256, 256, 0, stream>>>(feat, offs, rec);
    combine_k<<<1024, 256, 0, stream>>>(feat, offs, rec);
    transpose_k<<<NVOX / 64, 256, 0, stream>>>(feat, out);
}

// Round 6
// 248.840 us; speedup vs baseline: 3.3162x; 1.0944x over previous
//
#include <hip/hip_runtime.h>
#include <cmath>

#define CIN   512
#define COUT  64
#define DBINS 41
#define NFEAT 105   // DBINS + COUT
#define HF    16
#define WF    44
#define NPIX  704   // HF*WF
#define NCAM  24    // B*N
#define NXG   128
#define NVOX  16384 // 128*128 (NX2 == 1)
#define ROWF  210   // per-pixel feat row
#define BEVOF 146   // row tail offset: 64-float BEV accumulator per voxel
#define NPAIR (NCAM * NPIX * DBINS)  // 692736

// Workspace layout (bytes) — identical to round 4/5 (validated size):
#define WS_FEAT 8192
#define WS_CNT  14200832
#define WS_OFFS 14266368
#define WS_REC  14331904

// ---------------------------------------------------------------- utilities
__device__ __forceinline__ void inv3(const double a[9], double o[9]) {
    double c00 =  a[4]*a[8] - a[5]*a[7];
    double c01 = -(a[3]*a[8] - a[5]*a[6]);
    double c02 =  a[3]*a[7] - a[4]*a[6];
    double det = a[0]*c00 + a[1]*c01 + a[2]*c02;
    double id  = 1.0 / det;
    o[0] = c00 * id;
    o[1] = -(a[1]*a[8] - a[2]*a[7]) * id;
    o[2] =  (a[1]*a[5] - a[2]*a[4]) * id;
    o[3] = c01 * id;
    o[4] =  (a[0]*a[8] - a[2]*a[6]) * id;
    o[5] = -(a[0]*a[5] - a[2]*a[3]) * id;
    o[6] = c02 * id;
    o[7] = -(a[0]*a[7] - a[1]*a[6]) * id;
    o[8] =  (a[0]*a[4] - a[1]*a[3]) * id;
}

// --------------------------------------------------------- per-camera setup
__global__ void setup_cams_k(const float* __restrict__ rots,
                             const float* __restrict__ trans,
                             const float* __restrict__ intrins,
                             const float* __restrict__ post_rots,
                             const float* __restrict__ post_trans,
                             double* __restrict__ cams) {
    int i = blockIdx.x * blockDim.x + threadIdx.x;
    if (i >= NCAM) return;
    double R[9], K[9], PR[9], Kinv[9], PRinv[9];
    for (int k = 0; k < 9; ++k) {
        R[k]  = (double)rots[i*9 + k];
        K[k]  = (double)intrins[i*9 + k];
        PR[k] = (double)post_rots[i*9 + k];
    }
    inv3(K, Kinv);
    inv3(PR, PRinv);
    double* o = cams + (size_t)i * 24;
    for (int k = 0; k < 9; ++k) o[k] = PRinv[k];
    o[9]  = (double)post_trans[i*3 + 0];
    o[10] = (double)post_trans[i*3 + 1];
    o[11] = (double)post_trans[i*3 + 2];
    for (int r = 0; r < 3; ++r)
        for (int c = 0; c < 3; ++c)
            o[12 + r*3 + c] = R[r*3+0]*Kinv[0*3+c] + R[r*3+1]*Kinv[1*3+c] + R[r*3+2]*Kinv[2*3+c];
    o[21] = (double)trans[i*3 + 0];
    o[22] = (double)trans[i*3 + 1];
    o[23] = (double)trans[i*3 + 2];
}

// --------------------------------------------------------------- 1x1 conv GEMM
// Software-pipelined: kt+1's global loads issue into registers before kt's
// compute, hiding HBM latency under the FMA phase. Compute/epilogue identical
// to round 5.
__global__ __launch_bounds__(512) void gemm_feat_k(const float* __restrict__ x,
                                                   const float* __restrict__ w,
                                                   const float* __restrict__ bias,
                                                   float* __restrict__ feat) {
    __shared__ float xs[16][64][4];
    __shared__ float wsm[64 * 113];

    int bx   = blockIdx.x;
    int kh   = bx & 1;
    int tile = bx >> 1;
    int bn   = tile / 11;
    int p0   = (tile - bn * 11) * 64;
    int lane = threadIdx.x & 63;
    int wid  = threadIdx.x >> 6;

    // staging coordinates
    int px  = threadIdx.x & 63;
    int kq0 = threadIdx.x >> 6;          // stages kq0 and kq0+8
    int wo  = threadIdx.x >> 4;          // 0..31, stages o = wo + p*32
    int wci = (threadIdx.x & 15) << 2;

    const float* gx = x + ((size_t)bn * CIN + kh * 256 + (kq0 << 2)) * NPIX + p0 + px;

    float  xr[8];
    float4 wr[4];

    auto loadX = [&](int kt) {
        const float* g = gx + (size_t)kt * 64 * NPIX;
        #pragma unroll
        for (int j = 0; j < 4; ++j) xr[j]     = g[(size_t)j * NPIX];
        #pragma unroll
        for (int j = 0; j < 4; ++j) xr[4 + j] = g[(size_t)(32 + j) * NPIX];
    };
    auto loadW = [&](int kt) {
        int kbase = kh * 256 + kt * 64;
        #pragma unroll
        for (int p = 0; p < 4; ++p) {
            int o = wo + p * 32;
            wr[p] = make_float4(0.f, 0.f, 0.f, 0.f);
            if (o < 105)
                wr[p] = *reinterpret_cast<const float4*>(w + (size_t)o * CIN + kbase + wci);
        }
    };

    float acc[14];
    #pragma unroll
    for (int i = 0; i < 14; ++i) acc[i] = 0.0f;

    loadX(0);
    loadW(0);

    for (int kt = 0; kt < 4; ++kt) {
        if (kt) __syncthreads();          // prior compute done reading LDS
        // registers -> LDS
        #pragma unroll
        for (int j = 0; j < 4; ++j) xs[kq0][px][j]     = xr[j];
        #pragma unroll
        for (int j = 0; j < 4; ++j) xs[kq0 + 8][px][j] = xr[4 + j];
        #pragma unroll
        for (int p = 0; p < 4; ++p) {
            int o = wo + p * 32;
            if (o < 112) *reinterpret_cast<float4*>(&wsm[o * 64 + wci]) = wr[p];
        }
        __syncthreads();
        if (kt < 3) { loadX(kt + 1); loadW(kt + 1); }   // in flight during compute
        // ---- compute (identical to round 5)
        #pragma unroll 4
        for (int kq = 0; kq < 16; ++kq) {
            float4 xv = *reinterpret_cast<const float4*>(&xs[kq][lane][0]);
            #pragma unroll
            for (int i = 0; i < 14; ++i) {
                float4 wv = *reinterpret_cast<const float4*>(&wsm[(wid * 14 + i) * 64 + (kq << 2)]);
                acc[i] = fmaf(xv.x, wv.x, acc[i]);
                acc[i] = fmaf(xv.y, wv.y, acc[i]);
                acc[i] = fmaf(xv.z, wv.z, acc[i]);
                acc[i] = fmaf(xv.w, wv.w, acc[i]);
            }
        }
    }
    __syncthreads();

    #pragma unroll
    for (int i = 0; i < 14; ++i) {
        int o = wid * 14 + i;
        if (o < NFEAT) {
            float b = (kh == 0) ? bias[o] : 0.0f;
            wsm[lane * 113 + o] = acc[i] + b;
        }
    }
    __syncthreads();
    float* dst = feat + ((size_t)bn * NPIX + p0) * ROWF + kh * NFEAT;
    for (int idx = threadIdx.x; idx < 64 * NFEAT; idx += 512) {
        int pxx = idx / NFEAT;
        int o   = idx - pxx * NFEAT;
        dst[(size_t)pxx * ROWF + o] = wsm[pxx * 113 + o];
    }
}

// -------------------------------------------- softmax + geometry, in-place
__global__ __launch_bounds__(64) void phaseA_k(float* __restrict__ feat,
                                               const double* __restrict__ cams,
                                               int* __restrict__ cnt) {
    int pix = blockIdx.x;
    int bn  = pix / NPIX;
    int p   = pix - bn * NPIX;
    int h   = p / WF;
    int wpx = p - h * WF;
    int lane = threadIdx.x;

    __shared__ float f[NFEAT];
    float* row = feat + (size_t)pix * ROWF;
    for (int o = lane; o < NFEAT; o += 64) f[o] = row[o] + row[NFEAT + o];
    __syncthreads();

    float v = (lane < DBINS) ? f[lane] : -1e30f;
    float m = v;
    #pragma unroll
    for (int o = 32; o > 0; o >>= 1) m = fmaxf(m, __shfl_xor(m, o, 64));
    float e = (lane < DBINS) ? expf(v - m) : 0.0f;
    float s = e;
    #pragma unroll
    for (int o = 32; o > 0; o >>= 1) s += __shfl_xor(s, o, 64);

    if (lane < DBINS) {
        float pd = e / s;
        const double* cm = cams + (size_t)bn * 24;
        double dd = 4.0 + (double)lane;
        double ax = (double)wpx - cm[9];
        double ay = (double)h   - cm[10];
        double az = dd          - cm[11];
        double q0 = cm[0]*ax + cm[1]*ay + cm[2]*az;
        double q1 = cm[3]*ax + cm[4]*ay + cm[5]*az;
        double q2 = cm[6]*ax + cm[7]*ay + cm[8]*az;
        double r0 = q0 * q2, r1 = q1 * q2, r2 = q2;
        double sx = cm[12]*r0 + cm[13]*r1 + cm[14]*r2 + cm[21];
        double sy = cm[15]*r0 + cm[16]*r1 + cm[17]*r2 + cm[22];
        double sz = cm[18]*r0 + cm[19]*r1 + cm[20]*r2 + cm[23];
        int cx = (int)((sx + 50.8) / 0.8);   // trunc == .astype(int32)
        int cy = (int)((sy + 50.8) / 0.8);
        int cz = (int)(sz / 20.0);
        bool ok = (cx >= 0) && (cx < NXG) && (cy >= 0) && (cy < NXG) && (cz == 0);
        int rk = ok ? (cy * NXG + cx) : -1;
        row[64 + lane] = pd;
        ((int*)row)[105 + lane] = rk;
        if (rk >= 0) atomicAdd(&cnt[rk], 1);
    }
    row[lane] = f[DBINS + lane];
    row[BEVOF + lane] = 0.0f;
}

// ------------------------------------------------- exclusive scan of cnt
__global__ __launch_bounds__(1024) void scan_k(const int* __restrict__ cnt,
                                               int* __restrict__ offs) {
    __shared__ int sc[1024];
    int t = threadIdx.x;
    int loc[16];
    int s = 0;
    #pragma unroll
    for (int j = 0; j < 16; ++j) { loc[j] = cnt[t*16 + j]; s += loc[j]; }
    sc[t] = s;
    __syncthreads();
    for (int off = 1; off < 1024; off <<= 1) {
        int add = (t >= off) ? sc[t - off] : 0;
        __syncthreads();
        sc[t] += add;
        __syncthreads();
    }
    int base = sc[t] - s;
    #pragma unroll
    for (int j = 0; j < 16; ++j) { offs[t*16 + j] = base; base += loc[j]; }
}

// ------------------------------------------------- place pairs into segments
__global__ __launch_bounds__(256) void place_k(const float* __restrict__ feat,
                                               int* __restrict__ offs,
                                               unsigned* __restrict__ rec) {
    int i = blockIdx.x * 256 + threadIdx.x;
    if (i >= NPAIR) return;
    int pix = i / DBINS;
    int d   = i - pix * DBINS;
    const int* rowI = (const int*)(feat + (size_t)pix * ROWF);
    int r = rowI[105 + d];
    if (r >= 0) {
        int pos = atomicAdd(&offs[r], 1);
        rec[pos] = ((unsigned)pix << 6) | (unsigned)d;
    }
}

// ------------------------------------- entry-parallel segmented combine
// Fast path for full chunks: prefetch all 32 channel loads (independent,
// coalesced) before the accumulate/flush loop. Same FMA and flush order.
__global__ __launch_bounds__(256) void combine_k(float* __restrict__ feat,
                                                 const int* __restrict__ offs,
                                                 const unsigned* __restrict__ rec) {
    int ncnt = offs[NVOX - 1];
    int lane = threadIdx.x & 63;
    int wave = (blockIdx.x << 2) + (threadIdx.x >> 6);
    int nwav = gridDim.x << 2;
    int nchunk = (ncnt + 31) >> 5;

    for (int ch = wave; ch < nchunk; ch += nwav) {
        int i0 = ch << 5;
        int n  = min(32, ncnt - i0);
        int   rv = -1, pv = 0;
        float wv = 0.0f;
        if (lane < n) {
            unsigned e = rec[i0 + lane];
            pv = (int)(e >> 6);
            int d = (int)(e & 63u);
            const float* row = feat + (size_t)pv * ROWF;
            rv = ((const int*)row)[105 + d];
            wv = row[64 + d];
        }
        float acc = 0.0f;
        if (n == 32) {
            float xv[32];
            #pragma unroll
            for (int j = 0; j < 32; ++j) {
                int pj = __shfl(pv, j, 64);
                xv[j] = feat[(size_t)pj * ROWF + lane];
            }
            #pragma unroll
            for (int j = 0; j < 32; ++j) {
                int   rj = __shfl(rv, j, 64);
                float wj = __shfl(wv, j, 64);
                acc = fmaf(wj, xv[j], acc);
                int rn = __shfl(rv, (j + 1) & 31, 64);
                if (j == 31 || rn != rj) {
                    atomicAdd(&feat[(size_t)rj * ROWF + BEVOF + lane], acc);
                    acc = 0.0f;
                }
            }
        } else {
            for (int j = 0; j < n; ++j) {
                int   rj = __shfl(rv, j, 64);
                float wj = __shfl(wv, j, 64);
                int   pj = __shfl(pv, j, 64);
                acc = fmaf(wj, feat[(size_t)pj * ROWF + lane], acc);
                int rn = __shfl(rv, (j + 1) & 31, 64);
                if (j == n - 1 || rn != rj) {
                    atomicAdd(&feat[(size_t)rj * ROWF + BEVOF + lane], acc);
                    acc = 0.0f;
                }
            }
        }
    }
}

// -------------------------------------------------------- bev tails -> out
__global__ __launch_bounds__(256) void transpose_k(const float* __restrict__ feat,
                                                   float* __restrict__ out) {
    __shared__ float t[64][65];
    int r0 = blockIdx.x * 64;
    int c  = threadIdx.x & 63;
    int r4 = threadIdx.x >> 6;
    #pragma unroll
    for (int i = 0; i < 16; ++i) {
        int r = r4 + i * 4;
        t[r][c] = feat[(size_t)(r0 + r) * ROWF + BEVOF + c];
    }
    __syncthreads();
    int rl  = threadIdx.x & 63;
    int cc0 = threadIdx.x >> 6;
    #pragma unroll
    for (int i = 0; i < 16; ++i) {
        int ch = cc0 + i * 4;
        out[(size_t)ch * NVOX + r0 + rl] = t[rl][ch];
    }
}

// --------------------------------------------------------------------- launch
extern "C" void kernel_launch(void* const* d_in, const int* in_sizes, int n_in,
                              void* d_out, int out_size, void* d_ws, size_t ws_size,
                              hipStream_t stream) {
    const float* img   = (const float*)d_in[0];
    const float* dw    = (const float*)d_in[1];
    const float* db    = (const float*)d_in[2];
    const float* rots  = (const float*)d_in[3];
    const float* trans = (const float*)d_in[4];
    const float* intr  = (const float*)d_in[5];
    const float* prot  = (const float*)d_in[6];
    const float* ptrn  = (const float*)d_in[7];
    float* out = (float*)d_out;

    char* ws = (char*)d_ws;
    double*   cams = (double*)ws;
    float*    feat = (float*)(ws + WS_FEAT);
    int*      cnt  = (int*)(ws + WS_CNT);
    int*      offs = (int*)(ws + WS_OFFS);
    unsigned* rec  = (unsigned*)(ws + WS_REC);

    hipMemsetAsync(cnt, 0, NVOX * sizeof(int), stream);
    setup_cams_k<<<1, 64, 0, stream>>>(rots, trans, intr, prot, ptrn, cams);
    gemm_feat_k<<<528, 512, 0, stream>>>(img, dw, db, feat);
    phaseA_k<<<NCAM * NPIX, 64, 0, stream>>>(feat, cams, cnt);
    scan_k<<<1, 1024, 0, stream>>>(cnt, offs);
    place_k<<<(NPAIR + 255) / 256, 256, 0, stream>>>(feat, offs, rec);
    combine_k<<<2048, 256, 0, stream>>>(feat, offs, rec);
    transpose_k<<<NVOX / 64, 256, 0, stream>>>(feat, out);
}